// Round 1
// baseline (1097.795 us; speedup 1.0000x reference)
//
#include <hip/hip_runtime.h>
#include <hip/hip_bf16.h>
#include <math.h>

#define S_LEN   2048
#define H_DIM   1024
#define N_QH    16
#define N_KVH   8
#define HEADD   64
#define FF_DIM  2048
#define N_EXP   4
#define WIN     512
#define QB      16

typedef __attribute__((ext_vector_type(8))) short bf16x8;
typedef __attribute__((ext_vector_type(4))) float f32x4;

__device__ __forceinline__ short f2bf(float x) {
  unsigned u = __float_as_uint(x);
  u += 0x7fffu + ((u >> 16) & 1u);
  return (short)(u >> 16);
}

// ---------------- rope tables in fp64 (match np/fp64 reference closely) ----------------
__global__ __launch_bounds__(256) void k_rope_tables(float* __restrict__ ct, float* __restrict__ st) {
  int i = blockIdx.x * 256 + threadIdx.x;   // t*32+d, 2048*32 total
  int t = i >> 5, d = i & 31;
  double inv = 1.0 / pow(10000.0, (double)d / 32.0);
  double ang = (double)t * inv;
  ct[i] = (float)cos(ang);
  st[i] = (float)sin(ang);
}

// ---------------- rmsnorm over H=1024, optional bf16 dual-write ----------------
template <int WRITE_BF16>
__global__ __launch_bounds__(256) void k_rmsnorm(const float* __restrict__ x,
                                                 const float* __restrict__ w,
                                                 float* __restrict__ y,
                                                 short* __restrict__ ybf) {
  int row = blockIdx.x;
  const float4 v = ((const float4*)(x + (long)row * H_DIM))[threadIdx.x];
  float ss = v.x * v.x + v.y * v.y + v.z * v.z + v.w * v.w;
  for (int off = 32; off; off >>= 1) ss += __shfl_xor(ss, off);
  __shared__ float red[4];
  if ((threadIdx.x & 63) == 0) red[threadIdx.x >> 6] = ss;
  __syncthreads();
  ss = red[0] + red[1] + red[2] + red[3];
  float r = (float)(1.0 / sqrt((double)ss * (1.0 / 1024.0) + 1e-5));
  const float4 wv = ((const float4*)w)[threadIdx.x];
  float4 o;
  o.x = v.x * r * wv.x; o.y = v.y * r * wv.y; o.z = v.z * r * wv.z; o.w = v.w * r * wv.w;
  ((float4*)(y + (long)row * H_DIM))[threadIdx.x] = o;
  if (WRITE_BF16) {
    unsigned lo = (unsigned short)f2bf(o.x) | ((unsigned)(unsigned short)f2bf(o.y) << 16);
    unsigned hi = (unsigned short)f2bf(o.z) | ((unsigned)(unsigned short)f2bf(o.w) << 16);
    ((uint2*)(ybf + (long)row * H_DIM))[threadIdx.x] = make_uint2(lo, hi);
  }
}

// ---------------- fp32 GEMM: C[:, cOff+...] (+R) = A[M,K] @ B[K,N]; tile 128x64x16 ----------------
template <int ADD>
__global__ __launch_bounds__(256) void k_gemm_f32(const float* __restrict__ A,
                                                  const float* __restrict__ B,
                                                  const float* __restrict__ R,
                                                  float* __restrict__ C,
                                                  int K, int ldA, int ldB, int ldC, int cOff) {
  __shared__ float At[16][132];
  __shared__ float Bs[16][68];
  const int r0 = blockIdx.x * 128, c0 = blockIdx.y * 64;
  const int tid = threadIdx.x;
  const int tx = tid & 15, ty = tid >> 4;
  float acc[8][4];
#pragma unroll
  for (int i = 0; i < 8; i++)
#pragma unroll
    for (int j = 0; j < 4; j++) acc[i][j] = 0.f;
  for (int k0 = 0; k0 < K; k0 += 16) {
#pragma unroll
    for (int it = 0; it < 2; ++it) {
      int flat4 = tid + it * 256;                 // 512 float4 = 128x16
      int row = flat4 >> 2, c4 = (flat4 & 3) * 4;
      float4 a = *(const float4*)&A[(long)(r0 + row) * ldA + k0 + c4];
      At[c4 + 0][row] = a.x; At[c4 + 1][row] = a.y; At[c4 + 2][row] = a.z; At[c4 + 3][row] = a.w;
    }
    {
      int row = tid >> 4, c4 = (tid & 15) * 4;    // 256 float4 = 16x64
      *(float4*)&Bs[row][c4] = *(const float4*)&B[(long)(k0 + row) * ldB + c0 + c4];
    }
    __syncthreads();
#pragma unroll
    for (int k = 0; k < 16; ++k) {
      float4 b  = *(const float4*)&Bs[k][tx * 4];
      float4 a0 = *(const float4*)&At[k][ty * 8];
      float4 a1 = *(const float4*)&At[k][ty * 8 + 4];
      float av[8] = {a0.x, a0.y, a0.z, a0.w, a1.x, a1.y, a1.z, a1.w};
#pragma unroll
      for (int i = 0; i < 8; i++) {
        acc[i][0] += av[i] * b.x; acc[i][1] += av[i] * b.y;
        acc[i][2] += av[i] * b.z; acc[i][3] += av[i] * b.w;
      }
    }
    __syncthreads();
  }
#pragma unroll
  for (int i = 0; i < 8; i++) {
    long idx = (long)(r0 + ty * 8 + i) * ldC + cOff + c0 + tx * 4;
    float4 o = make_float4(acc[i][0], acc[i][1], acc[i][2], acc[i][3]);
    if (ADD) {
      float4 rv = *(const float4*)&R[idx];
      o.x += rv.x; o.y += rv.y; o.z += rv.z; o.w += rv.w;
    }
    *(float4*)&C[idx] = o;
  }
}

// ---------------- rope + per-head rms on q,k (in place on qkv buffer) ----------------
__global__ __launch_bounds__(256) void k_rope_rms(float* __restrict__ qkv,
                                                  const float* __restrict__ qn_w,
                                                  const float* __restrict__ kn_w,
                                                  const float* __restrict__ ct,
                                                  const float* __restrict__ st) {
  int idx = blockIdx.x * 4 + (threadIdx.x >> 6);  // head-slot 0 .. 2048*24-1
  int lane = threadIdx.x & 63;
  int t = idx / 24, hh = idx - t * 24;
  long base; const float* w;
  if (hh < N_QH) { base = (long)t * 2048 + hh * HEADD;              w = qn_w; }
  else           { base = (long)t * 2048 + 1024 + (hh - N_QH) * HEADD; w = kn_w; }
  float x = qkv[base + lane];
  float partner = __shfl_xor(x, 32);
  int d = lane & 31;
  float cs = ct[t * 32 + d], sn = st[t * 32 + d];
  float r = x * cs + partner * ((lane < 32) ? -sn : sn);
  float ss = r * r;
  for (int off = 32; off; off >>= 1) ss += __shfl_xor(ss, off);
  float rr = (float)(1.0 / sqrt((double)ss * (1.0 / 64.0) + 1e-5));
  qkv[base + lane] = r * rr * w[lane];
}

// ---------------- windowed attention, fp32, scores materialized in LDS ----------------
__global__ __launch_bounds__(256) void k_attn(const float* __restrict__ qkv,
                                              float* __restrict__ att) {
  __shared__ float q_s[QB][68];
  __shared__ float kv_s[64][68];
  __shared__ float sc[QB][584];
  __shared__ float row_a[QB];
  const int i0 = blockIdx.x * QB;
  const int hq = blockIdx.y;
  const int kvh = hq >> 1;
  const int tid = threadIdx.x;
  {
    int r = tid >> 4, c4 = (tid & 15) * 4;        // 256 float4 = 16x64
    *(float4*)&q_s[r][c4] = *(const float4*)&qkv[(long)(i0 + r) * 2048 + hq * HEADD + c4];
  }
  const int jstart = max(0, i0 - (WIN - 1));
  const int nch = (i0 + QB - jstart + 63) >> 6;   // <= 9
  const int q = tid >> 4, cc = tid & 15;
  const int i = i0 + q;
  for (int ch = 0; ch < nch; ++ch) {
    int jb = jstart + ch * 64;
#pragma unroll
    for (int it = 0; it < 4; ++it) {
      int flat4 = tid + it * 256;                 // 1024 float4 = 64x16
      int r = flat4 >> 4, c4 = (flat4 & 15) * 4;
      int j = jb + r;
      float4 kvv = make_float4(0.f, 0.f, 0.f, 0.f);
      if (j < S_LEN) kvv = *(const float4*)&qkv[(long)j * 2048 + 1024 + kvh * HEADD + c4];
      *(float4*)&kv_s[r][c4] = kvv;
    }
    __syncthreads();
#pragma unroll
    for (int m = 0; m < 4; ++m) {
      int jl = cc + m * 16;
      int j = jb + jl;
      float s = 0.f;
#pragma unroll
      for (int d4 = 0; d4 < 16; ++d4) {
        float4 qv = *(const float4*)&q_s[q][d4 * 4];
        float4 kv = *(const float4*)&kv_s[jl][d4 * 4];
        s += qv.x * kv.x + qv.y * kv.y + qv.z * kv.z + qv.w * kv.w;
      }
      s *= 0.125f;                     // 1/sqrt(64)
      s = 50.f * tanhf(s * 0.02f);     // softcap
      bool allow = (j <= i) && (i - j < WIN);
      sc[q][ch * 64 + jl] = allow ? s : -1e30f;
    }
    __syncthreads();
  }
  {
    int wid = tid >> 6, lane = tid & 63;
    int ncols = nch * 64;
    for (int r = wid * 4; r < wid * 4 + 4; ++r) {
      float mx = -1e30f;
      for (int n = lane; n < ncols; n += 64) mx = fmaxf(mx, sc[r][n]);
      for (int off = 32; off; off >>= 1) mx = fmaxf(mx, __shfl_xor(mx, off));
      float sum = 0.f;
      for (int n = lane; n < ncols; n += 64) {
        float p = expf(sc[r][n] - mx);
        sc[r][n] = p; sum += p;
      }
      for (int off = 32; off; off >>= 1) sum += __shfl_xor(sum, off);
      if (lane == 0) row_a[r] = 1.06f / sum;
    }
  }
  __syncthreads();
  float outv[4] = {0.f, 0.f, 0.f, 0.f};
  for (int ch = 0; ch < nch; ++ch) {
    int jb = jstart + ch * 64;
#pragma unroll
    for (int it = 0; it < 4; ++it) {
      int flat4 = tid + it * 256;
      int r = flat4 >> 4, c4 = (flat4 & 15) * 4;
      int j = jb + r;
      float4 vv = make_float4(0.f, 0.f, 0.f, 0.f);
      if (j < S_LEN) vv = *(const float4*)&qkv[(long)j * 2048 + 1536 + kvh * HEADD + c4];
      *(float4*)&kv_s[r][c4] = vv;
    }
    __syncthreads();
    float a = row_a[q];
    for (int jl = 0; jl < 64; ++jl) {
      float p = sc[q][ch * 64 + jl];
      p = fminf(fmaxf(fmaf(a, p, -0.03f), 0.f), 1.f);   // clip(1.06*p/l - 0.03, 0, 1)
      float4 vv = *(const float4*)&kv_s[jl][cc * 4];
      outv[0] += p * vv.x; outv[1] += p * vv.y; outv[2] += p * vv.z; outv[3] += p * vv.w;
    }
    __syncthreads();
  }
  *(float4*)&att[(long)i * 1024 + hq * HEADD + cc * 4] =
      make_float4(outv[0], outv[1], outv[2], outv[3]);
}

// ---------------- gate / top-2 routing (fp32, exact-order-safe) ----------------
__global__ __launch_bounds__(256) void k_gate(const float* __restrict__ x2f,
                                              const float* __restrict__ gw,
                                              float* __restrict__ wd) {
  int t = blockIdx.x;
  float p0 = 0, p1 = 0, p2 = 0, p3 = 0;
  for (int ii = threadIdx.x; ii < H_DIM; ii += 256) {
    float xv = x2f[(long)t * H_DIM + ii];
    float4 g = *(const float4*)&gw[ii * 4];
    p0 += xv * g.x; p1 += xv * g.y; p2 += xv * g.z; p3 += xv * g.w;
  }
  for (int off = 32; off; off >>= 1) {
    p0 += __shfl_xor(p0, off); p1 += __shfl_xor(p1, off);
    p2 += __shfl_xor(p2, off); p3 += __shfl_xor(p3, off);
  }
  __shared__ float red[4][4];
  int wid = threadIdx.x >> 6;
  if ((threadIdx.x & 63) == 0) { red[wid][0] = p0; red[wid][1] = p1; red[wid][2] = p2; red[wid][3] = p3; }
  __syncthreads();
  if (threadIdx.x == 0) {
    float l[4];
    for (int e = 0; e < 4; ++e) l[e] = red[0][e] + red[1][e] + red[2][e] + red[3][e];
    int i1 = 0;
    for (int e = 1; e < 4; ++e) if (l[e] > l[i1]) i1 = e;          // lowest index on ties
    int i2 = -1;
    for (int e = 0; e < 4; ++e) { if (e == i1) continue; if (i2 < 0 || l[e] > l[i2]) i2 = e; }
    float e2 = expf(l[i2] - l[i1]);
    float w1 = 1.f / (1.f + e2);
    float o[4] = {0.f, 0.f, 0.f, 0.f};
    o[i1] = w1; o[i2] = 1.f - w1;
    wd[t * 4 + 0] = o[0]; wd[t * 4 + 1] = o[1]; wd[t * 4 + 2] = o[2]; wd[t * 4 + 3] = o[3];
  }
}

// ---------------- transpose + cast fp32(R,C) -> bf16(C,R) ----------------
__global__ __launch_bounds__(256) void k_transpose_cast(const float* __restrict__ in,
                                                        short* __restrict__ out,
                                                        int R, int C) {
  __shared__ float tile[32][33];
  int bx = blockIdx.x, by = blockIdx.y;
  int lx = threadIdx.x & 31, ly = threadIdx.x >> 5;
  int x = bx * 32 + lx;
#pragma unroll
  for (int k = 0; k < 4; ++k) {
    int y = by * 32 + ly + k * 8;
    tile[ly + k * 8][lx] = in[(long)y * C + x];
  }
  __syncthreads();
  int ox = by * 32 + lx;
#pragma unroll
  for (int k = 0; k < 4; ++k) {
    int oy = bx * 32 + ly + k * 8;
    out[(long)oy * R + ox] = f2bf(tile[lx][ly + k * 8]);
  }
}

// ---------------- bf16 MFMA GEMM: C[M,N](f32) (+)= A[M,K] @ Bt[N,K]^T ----------------
template <int ATOMIC>
__global__ __launch_bounds__(256) void k_gemm_bf16(const short* __restrict__ A,
                                                   const short* __restrict__ Bt,
                                                   float* __restrict__ C,
                                                   int K, int ldA, int ldB, int ldC,
                                                   long sA, long sB, long sC) {
  __shared__ short As[128][72];
  __shared__ short Bs[128][72];
  const int e = blockIdx.z;
  A += (long)e * sA; Bt += (long)e * sB; C += (long)e * sC;
  const int r0 = blockIdx.x * 128, c0 = blockIdx.y * 128;
  const int tid = threadIdx.x;
  const int wid = tid >> 6, lane = tid & 63;
  const int wr = wid >> 1, wc = wid & 1;
  const int lr = lane & 15, lg = lane >> 4;
  f32x4 zero = {0.f, 0.f, 0.f, 0.f};
  f32x4 acc[4][4];
#pragma unroll
  for (int m = 0; m < 4; ++m)
#pragma unroll
    for (int n = 0; n < 4; ++n) acc[m][n] = zero;
  for (int k0 = 0; k0 < K; k0 += 64) {
#pragma unroll
    for (int it = 0; it < 4; ++it) {
      int flat = tid + it * 256;
      int row = flat >> 3, cb = (flat & 7) * 8;
      *(uint4*)&As[row][cb] = *(const uint4*)&A[(long)(r0 + row) * ldA + k0 + cb];
      *(uint4*)&Bs[row][cb] = *(const uint4*)&Bt[(long)(c0 + row) * ldB + k0 + cb];
    }
    __syncthreads();
#pragma unroll
    for (int kk = 0; kk < 64; kk += 32) {
      bf16x8 af[4], bfr[4];
#pragma unroll
      for (int m = 0; m < 4; ++m) af[m] = *(const bf16x8*)&As[wr * 64 + m * 16 + lr][kk + lg * 8];
#pragma unroll
      for (int n = 0; n < 4; ++n) bfr[n] = *(const bf16x8*)&Bs[wc * 64 + n * 16 + lr][kk + lg * 8];
#pragma unroll
      for (int m = 0; m < 4; ++m)
#pragma unroll
        for (int n = 0; n < 4; ++n)
          acc[m][n] = __builtin_amdgcn_mfma_f32_16x16x32_bf16(af[m], bfr[n], acc[m][n], 0, 0, 0);
    }
    __syncthreads();
  }
#pragma unroll
  for (int m = 0; m < 4; ++m)
#pragma unroll
    for (int n = 0; n < 4; ++n) {
      int col = c0 + wc * 64 + n * 16 + lr;
#pragma unroll
      for (int r = 0; r < 4; ++r) {
        int row = r0 + wr * 64 + m * 16 + lg * 4 + r;
        float v = acc[m][n][r];
        if (ATOMIC) atomicAdd(&C[(long)row * ldC + col], v);
        else        C[(long)row * ldC + col] = v;
      }
    }
}

// ---------------- moe activation: a[e,t,f] = bf16( silu(g)*u * w_te ) ----------------
__global__ __launch_bounds__(256) void k_moe_act(const float* __restrict__ gu,
                                                 const float* __restrict__ wd,
                                                 short* __restrict__ aAll,
                                                 int e) {
  long i4 = (long)blockIdx.x * 256 + threadIdx.x;   // 2048*2048/4 = 1M float4
  int t  = (int)(i4 >> 9);
  int f4 = (int)(i4 & 511);
  float wte = wd[t * 4 + e];
  float4 g = ((const float4*)gu)[(long)t * 1024 + f4];
  float4 u = ((const float4*)gu)[(long)t * 1024 + 512 + f4];
  float4 s;
  s.x = wte * u.x * g.x / (1.f + expf(-g.x));
  s.y = wte * u.y * g.y / (1.f + expf(-g.y));
  s.z = wte * u.z * g.z / (1.f + expf(-g.z));
  s.w = wte * u.w * g.w / (1.f + expf(-g.w));
  unsigned lo = (unsigned short)f2bf(s.x) | ((unsigned)(unsigned short)f2bf(s.y) << 16);
  unsigned hi = (unsigned short)f2bf(s.z) | ((unsigned)(unsigned short)f2bf(s.w) << 16);
  ((uint2*)(aAll + ((long)e << 22)))[i4] = make_uint2(lo, hi);
}

extern "C" void kernel_launch(void* const* d_in, const int* in_sizes, int n_in,
                              void* d_out, int out_size, void* d_ws, size_t ws_size,
                              hipStream_t stream) {
  const float* x       = (const float*)d_in[0];
  const float* norm1_w = (const float*)d_in[1];
  const float* wq      = (const float*)d_in[2];
  const float* wk      = (const float*)d_in[3];
  const float* wv      = (const float*)d_in[4];
  const float* wo      = (const float*)d_in[5];
  const float* qn_w    = (const float*)d_in[6];
  const float* kn_w    = (const float*)d_in[7];
  const float* norm2_w = (const float*)d_in[8];
  const float* gate_w  = (const float*)d_in[9];
  const float* w_gate  = (const float*)d_in[10];
  const float* w_up    = (const float*)d_in[11];
  const float* w_down  = (const float*)d_in[12];
  float* out = (float*)d_out;
  char* ws = (char*)d_ws;
  const unsigned long MB = 1ul << 20;

  float* ropeC = (float*)(ws + 0);
  float* ropeS = (float*)(ws + 256 * 1024);
  float* xn    = (float*)(ws + 1 * MB);    // 8 MB
  float* qkv   = (float*)(ws + 9 * MB);    // 16 MB
  float* att   = (float*)(ws + 25 * MB);   // 8 MB
  float* gu    = (float*)(ws + 1 * MB);    // 32 MB, aliases xn/qkv/att (dead by MoE phase)
  float* h     = (float*)(ws + 33 * MB);   // 8 MB
  float* x2f   = (float*)(ws + 41 * MB);   // 8 MB
  short* x2b   = (short*)(ws + 49 * MB);   // 4 MB
  float* wd    = (float*)(ws + 53 * MB);   // 32 KB
  short* dT    = (short*)(ws + 54 * MB);   // 16 MB
  short* guT   = (short*)(ws + 70 * MB);   // 8 MB (per-expert reuse)
  short* aAll  = (short*)(ws + 78 * MB);   // 32 MB  (total 110 MB)

  k_rope_tables<<<256, 256, 0, stream>>>(ropeC, ropeS);
  k_rmsnorm<0><<<S_LEN, 256, 0, stream>>>(x, norm1_w, xn, nullptr);
  // fp32 QKV projections into combined qkv buffer (ld 2048): q|k|v at col 0|1024|1536
  k_gemm_f32<0><<<dim3(16, 16), 256, 0, stream>>>(xn, wq, nullptr, qkv, 1024, 1024, 1024, 2048, 0);
  k_gemm_f32<0><<<dim3(16,  8), 256, 0, stream>>>(xn, wk, nullptr, qkv, 1024, 1024,  512, 2048, 1024);
  k_gemm_f32<0><<<dim3(16,  8), 256, 0, stream>>>(xn, wv, nullptr, qkv, 1024, 1024,  512, 2048, 1536);
  k_rope_rms<<<(S_LEN * 24) / 4, 256, 0, stream>>>(qkv, qn_w, kn_w, ropeC, ropeS);
  k_attn<<<dim3(S_LEN / QB, N_QH), 256, 0, stream>>>(qkv, att);
  // h = x + att @ wo   (fp32)
  k_gemm_f32<1><<<dim3(16, 16), 256, 0, stream>>>(att, wo, x, h, 1024, 1024, 1024, 1024, 0);
  k_rmsnorm<1><<<S_LEN, 256, 0, stream>>>(h, norm2_w, x2f, x2b);
  k_gate<<<S_LEN, 256, 0, stream>>>(x2f, gate_w, wd);
  hipMemcpyAsync(out, h, (size_t)S_LEN * H_DIM * sizeof(float), hipMemcpyDeviceToDevice, stream);
  // bf16 down-proj weights (all experts, needed by batched GEMM2)
  for (int e = 0; e < N_EXP; ++e)
    k_transpose_cast<<<dim3(1024 / 32, 2048 / 32), 256, 0, stream>>>(
        w_down + (long)e * FF_DIM * H_DIM, dT + (long)e * H_DIM * FF_DIM, 2048, 1024);
  // per-expert: transpose gate/up -> guT, GEMM1 (N=4096), activation -> aAll[e]
  for (int e = 0; e < N_EXP; ++e) {
    k_transpose_cast<<<dim3(2048 / 32, 1024 / 32), 256, 0, stream>>>(
        w_gate + (long)e * H_DIM * FF_DIM, guT, 1024, 2048);
    k_transpose_cast<<<dim3(2048 / 32, 1024 / 32), 256, 0, stream>>>(
        w_up + (long)e * H_DIM * FF_DIM, guT + (long)FF_DIM * H_DIM, 1024, 2048);
    k_gemm_bf16<0><<<dim3(16, 32), 256, 0, stream>>>(x2b, guT, gu, 1024, 1024, 1024, 4096, 0, 0, 0);
    k_moe_act<<<4096, 256, 0, stream>>>(gu, wd, aAll, e);
  }
  // batched GEMM2 over experts: out += a[e] @ w_down[e]  (atomicAdd epilogue)
  k_gemm_bf16<1><<<dim3(16, 8, N_EXP), 256, 0, stream>>>(
      aAll, dT, out, 2048, 2048, 2048, 1024,
      (long)S_LEN * FF_DIM, (long)H_DIM * FF_DIM, 0);
}

// Round 3
// 716.625 us; speedup vs baseline: 1.5319x; 1.5319x over previous
//
#include <hip/hip_runtime.h>
#include <hip/hip_bf16.h>
#include <math.h>

#define S_LEN   2048
#define H_DIM   1024
#define N_QH    16
#define N_KVH   8
#define HEADD   64
#define FF_DIM  2048
#define N_EXP   4
#define WIN     512
#define QB      16

typedef __attribute__((ext_vector_type(8))) short bf16x8;
typedef __attribute__((ext_vector_type(4))) float f32x4;

__device__ __forceinline__ short f2bf(float x) {
  unsigned u = __float_as_uint(x);
  u += 0x7fffu + ((u >> 16) & 1u);
  return (short)(u >> 16);
}
__device__ __forceinline__ float bf2f(short h) {
  return __uint_as_float((unsigned)(unsigned short)h << 16);
}
// T2 XOR swizzle for [128][64]-short LDS tiles: bank-conflict-free ds_read_b128
// on the "16 lanes read 16 rows at same col" MFMA fragment pattern.
__device__ __forceinline__ int swz(int row, int col) {   // col in shorts, [0,64)
  return row * 64 + (col ^ ((row & 7) << 3));
}

// ---------------- rope tables in fp64 (match np/fp64 reference closely) ----------------
__global__ __launch_bounds__(256) void k_rope_tables(float* __restrict__ ct, float* __restrict__ st) {
  int i = blockIdx.x * 256 + threadIdx.x;   // t*32+d, 2048*32 total
  int t = i >> 5, d = i & 31;
  double inv = 1.0 / pow(10000.0, (double)d / 32.0);
  double ang = (double)t * inv;
  ct[i] = (float)cos(ang);
  st[i] = (float)sin(ang);
}

// ---------------- rmsnorm over H=1024 ----------------
// MODE 2: write split hi/lo bf16 (GEMM A operand)
// MODE 3: write single bf16 + fused gate top-2 routing -> wd
template <int MODE>
__global__ __launch_bounds__(256) void k_rmsnorm(const float* __restrict__ x,
                                                 const float* __restrict__ w,
                                                 short* __restrict__ yh,
                                                 short* __restrict__ yl,
                                                 const float* __restrict__ gw,
                                                 float* __restrict__ wd) {
  int row = blockIdx.x;
  const float4 v = ((const float4*)(x + (long)row * H_DIM))[threadIdx.x];
  float ss = v.x * v.x + v.y * v.y + v.z * v.z + v.w * v.w;
  for (int off = 32; off; off >>= 1) ss += __shfl_xor(ss, off);
  __shared__ float red[4];
  if ((threadIdx.x & 63) == 0) red[threadIdx.x >> 6] = ss;
  __syncthreads();
  ss = red[0] + red[1] + red[2] + red[3];
  float r = (float)(1.0 / sqrt((double)ss * (1.0 / 1024.0) + 1e-5));
  const float4 wv = ((const float4*)w)[threadIdx.x];
  float4 o;
  o.x = v.x * r * wv.x; o.y = v.y * r * wv.y; o.z = v.z * r * wv.z; o.w = v.w * r * wv.w;
  if (MODE == 2) {
    short h0 = f2bf(o.x), h1 = f2bf(o.y), h2 = f2bf(o.z), h3 = f2bf(o.w);
    short l0 = f2bf(o.x - bf2f(h0)), l1 = f2bf(o.y - bf2f(h1));
    short l2 = f2bf(o.z - bf2f(h2)), l3 = f2bf(o.w - bf2f(h3));
    uint2 hv = make_uint2((unsigned short)h0 | ((unsigned)(unsigned short)h1 << 16),
                          (unsigned short)h2 | ((unsigned)(unsigned short)h3 << 16));
    uint2 lv = make_uint2((unsigned short)l0 | ((unsigned)(unsigned short)l1 << 16),
                          (unsigned short)l2 | ((unsigned)(unsigned short)l3 << 16));
    ((uint2*)(yh + (long)row * H_DIM))[threadIdx.x] = hv;
    ((uint2*)(yl + (long)row * H_DIM))[threadIdx.x] = lv;
  }
  if (MODE == 3) {
    unsigned lo = (unsigned short)f2bf(o.x) | ((unsigned)(unsigned short)f2bf(o.y) << 16);
    unsigned hi = (unsigned short)f2bf(o.z) | ((unsigned)(unsigned short)f2bf(o.w) << 16);
    ((uint2*)(yh + (long)row * H_DIM))[threadIdx.x] = make_uint2(lo, hi);
    // fused gate: logits[e] = xn2 . gw[:,e]   (fp32, routing-critical)
    int i0 = threadIdx.x * 4;
    float4 g0 = *(const float4*)&gw[(i0 + 0) * 4];
    float4 g1 = *(const float4*)&gw[(i0 + 1) * 4];
    float4 g2 = *(const float4*)&gw[(i0 + 2) * 4];
    float4 g3 = *(const float4*)&gw[(i0 + 3) * 4];
    float p0 = o.x * g0.x + o.y * g1.x + o.z * g2.x + o.w * g3.x;
    float p1 = o.x * g0.y + o.y * g1.y + o.z * g2.y + o.w * g3.y;
    float p2 = o.x * g0.z + o.y * g1.z + o.z * g2.z + o.w * g3.z;
    float p3 = o.x * g0.w + o.y * g1.w + o.z * g2.w + o.w * g3.w;
    for (int off = 32; off; off >>= 1) {
      p0 += __shfl_xor(p0, off); p1 += __shfl_xor(p1, off);
      p2 += __shfl_xor(p2, off); p3 += __shfl_xor(p3, off);
    }
    __shared__ float gred[4][4];
    int wid = threadIdx.x >> 6;
    if ((threadIdx.x & 63) == 0) { gred[wid][0] = p0; gred[wid][1] = p1; gred[wid][2] = p2; gred[wid][3] = p3; }
    __syncthreads();
    if (threadIdx.x == 0) {
      float l[4];
      for (int e = 0; e < 4; ++e) l[e] = gred[0][e] + gred[1][e] + gred[2][e] + gred[3][e];
      int i1 = 0;
      for (int e = 1; e < 4; ++e) if (l[e] > l[i1]) i1 = e;          // lowest index on ties
      int i2 = -1;
      for (int e = 0; e < 4; ++e) { if (e == i1) continue; if (i2 < 0 || l[e] > l[i2]) i2 = e; }
      float e2 = expf(l[i2] - l[i1]);
      float w1 = 1.f / (1.f + e2);
      float ov[4] = {0.f, 0.f, 0.f, 0.f};
      ov[i1] = w1; ov[i2] = 1.f - w1;
      wd[row * 4 + 0] = ov[0]; wd[row * 4 + 1] = ov[1];
      wd[row * 4 + 2] = ov[2]; wd[row * 4 + 3] = ov[3];
    }
  }
}

// ---------------- transpose + split fp32(R,C) -> hi/lo bf16 (C,R) ----------------
__global__ __launch_bounds__(256) void k_tsplit(const float* __restrict__ in,
                                                short* __restrict__ oh,
                                                short* __restrict__ ol, int R, int C) {
  __shared__ float tile[32][33];
  int bx = blockIdx.x, by = blockIdx.y;
  int lx = threadIdx.x & 31, ly = threadIdx.x >> 5;
  int xc = bx * 32 + lx;
#pragma unroll
  for (int k = 0; k < 4; ++k) {
    int y = by * 32 + ly + k * 8;
    tile[ly + k * 8][lx] = in[(long)y * C + xc];
  }
  __syncthreads();
  int ox = by * 32 + lx;
#pragma unroll
  for (int k = 0; k < 4; ++k) {
    int oy = bx * 32 + ly + k * 8;
    float v = tile[lx][ly + k * 8];
    short hb = f2bf(v);
    short lb = f2bf(v - bf2f(hb));
    oh[(long)oy * R + ox] = hb;
    ol[(long)oy * R + ox] = lb;
  }
}

// ---------------- transpose + cast fp32(R,C) -> bf16(C,R) ----------------
__global__ __launch_bounds__(256) void k_transpose_cast(const float* __restrict__ in,
                                                        short* __restrict__ out,
                                                        int R, int C) {
  __shared__ float tile[32][33];
  int bx = blockIdx.x, by = blockIdx.y;
  int lx = threadIdx.x & 31, ly = threadIdx.x >> 5;
  int x = bx * 32 + lx;
#pragma unroll
  for (int k = 0; k < 4; ++k) {
    int y = by * 32 + ly + k * 8;
    tile[ly + k * 8][lx] = in[(long)y * C + x];
  }
  __syncthreads();
  int ox = by * 32 + lx;
#pragma unroll
  for (int k = 0; k < 4; ++k) {
    int oy = bx * 32 + ly + k * 8;
    out[(long)oy * R + ox] = f2bf(tile[lx][ly + k * 8]);
  }
}

// ---------------- split-bf16 "fp32" GEMM: C = Ahi.Bhi + Ahi.Blo + Alo.Bhi (+R) ----------------
// A (M,K) row-major split, Bt (N,K) row-major split (i.e. B^T), C fp32 (M,N)
template <int ADD>
__global__ __launch_bounds__(256) void k_gemm_split(const short* __restrict__ Ah,
                                                    const short* __restrict__ Al,
                                                    const short* __restrict__ Bh,
                                                    const short* __restrict__ Bl,
                                                    const float* __restrict__ R,
                                                    float* __restrict__ C,
                                                    int K, int ldA, int ldB, int ldC) {
  __shared__ short AsH[128 * 64], AsL[128 * 64], BsH[128 * 64], BsL[128 * 64];
  const int r0 = blockIdx.x * 128, c0 = blockIdx.y * 128;
  const int tid = threadIdx.x;
  const int wid = tid >> 6, lane = tid & 63;
  const int wr = wid >> 1, wc = wid & 1;
  const int lr = lane & 15, lg = lane >> 4;
  f32x4 zero = {0.f, 0.f, 0.f, 0.f};
  f32x4 acc[4][4];
#pragma unroll
  for (int m = 0; m < 4; ++m)
#pragma unroll
    for (int n = 0; n < 4; ++n) acc[m][n] = zero;
  for (int k0 = 0; k0 < K; k0 += 64) {
#pragma unroll
    for (int it = 0; it < 4; ++it) {
      int flat = tid + it * 256;
      int row = flat >> 3, cb = (flat & 7) * 8;
      int d = swz(row, cb);
      *(uint4*)&AsH[d] = *(const uint4*)&Ah[(long)(r0 + row) * ldA + k0 + cb];
      *(uint4*)&AsL[d] = *(const uint4*)&Al[(long)(r0 + row) * ldA + k0 + cb];
      *(uint4*)&BsH[d] = *(const uint4*)&Bh[(long)(c0 + row) * ldB + k0 + cb];
      *(uint4*)&BsL[d] = *(const uint4*)&Bl[(long)(c0 + row) * ldB + k0 + cb];
    }
    __syncthreads();
#pragma unroll
    for (int kk = 0; kk < 64; kk += 32) {
      bf16x8 ah[4], al[4], bh[4], bl[4];
#pragma unroll
      for (int m = 0; m < 4; ++m) {
        int d = swz(wr * 64 + m * 16 + lr, kk + lg * 8);
        ah[m] = *(const bf16x8*)&AsH[d];
        al[m] = *(const bf16x8*)&AsL[d];
      }
#pragma unroll
      for (int n = 0; n < 4; ++n) {
        int d = swz(wc * 64 + n * 16 + lr, kk + lg * 8);
        bh[n] = *(const bf16x8*)&BsH[d];
        bl[n] = *(const bf16x8*)&BsL[d];
      }
#pragma unroll
      for (int m = 0; m < 4; ++m)
#pragma unroll
        for (int n = 0; n < 4; ++n) {
          acc[m][n] = __builtin_amdgcn_mfma_f32_16x16x32_bf16(ah[m], bh[n], acc[m][n], 0, 0, 0);
          acc[m][n] = __builtin_amdgcn_mfma_f32_16x16x32_bf16(ah[m], bl[n], acc[m][n], 0, 0, 0);
          acc[m][n] = __builtin_amdgcn_mfma_f32_16x16x32_bf16(al[m], bh[n], acc[m][n], 0, 0, 0);
        }
    }
    __syncthreads();
  }
#pragma unroll
  for (int m = 0; m < 4; ++m)
#pragma unroll
    for (int n = 0; n < 4; ++n) {
      int col = c0 + wc * 64 + n * 16 + lr;
#pragma unroll
      for (int r = 0; r < 4; ++r) {
        int row = r0 + wr * 64 + m * 16 + lg * 4 + r;
        float v = acc[m][n][r];
        if (ADD) v += R[(long)row * ldC + col];
        C[(long)row * ldC + col] = v;
      }
    }
}

// ---------------- rope + per-head rms on q,k (in place on qkv buffer) ----------------
__global__ __launch_bounds__(256) void k_rope_rms(float* __restrict__ qkv,
                                                  const float* __restrict__ qn_w,
                                                  const float* __restrict__ kn_w,
                                                  const float* __restrict__ ct,
                                                  const float* __restrict__ st) {
  int idx = blockIdx.x * 4 + (threadIdx.x >> 6);  // head-slot 0 .. 2048*24-1
  int lane = threadIdx.x & 63;
  int t = idx / 24, hh = idx - t * 24;
  long base; const float* w;
  if (hh < N_QH) { base = (long)t * 2048 + hh * HEADD;              w = qn_w; }
  else           { base = (long)t * 2048 + 1024 + (hh - N_QH) * HEADD; w = kn_w; }
  float x = qkv[base + lane];
  float partner = __shfl_xor(x, 32);
  int d = lane & 31;
  float cs = ct[t * 32 + d], sn = st[t * 32 + d];
  float r = x * cs + partner * ((lane < 32) ? -sn : sn);
  float ss = r * r;
  for (int off = 32; off; off >>= 1) ss += __shfl_xor(ss, off);
  float rr = (float)(1.0 / sqrt((double)ss * (1.0 / 64.0) + 1e-5));
  qkv[base + lane] = r * rr * w[lane];
}

// ---------------- windowed attention, fp32, Q in registers, split-bf16 output ----------------
__global__ __launch_bounds__(256) void k_attn(const float* __restrict__ qkv,
                                              short* __restrict__ attHi,
                                              short* __restrict__ attLo) {
  __shared__ float kv_s[64][68];
  __shared__ float sc[QB][584];
  __shared__ float row_a[QB];
  const int i0 = blockIdx.x * QB;
  const int hq = blockIdx.y;
  const int kvh = hq >> 1;
  const int tid = threadIdx.x;
  const int q = tid >> 4, cc = tid & 15;
  const int i = i0 + q;
  float4 qreg[16];
#pragma unroll
  for (int d4 = 0; d4 < 16; ++d4)
    qreg[d4] = *(const float4*)&qkv[(long)i * 2048 + hq * HEADD + d4 * 4];
  const int jstart = max(0, i0 - (WIN - 1));
  const int nch = (i0 + QB - jstart + 63) >> 6;   // <= 9
  for (int ch = 0; ch < nch; ++ch) {
    int jb = jstart + ch * 64;
#pragma unroll
    for (int it = 0; it < 4; ++it) {
      int flat4 = tid + it * 256;                 // 1024 float4 = 64x16
      int r = flat4 >> 4, c4 = (flat4 & 15) * 4;
      int j = jb + r;
      float4 kvv = make_float4(0.f, 0.f, 0.f, 0.f);
      if (j < S_LEN) kvv = *(const float4*)&qkv[(long)j * 2048 + 1024 + kvh * HEADD + c4];
      *(float4*)&kv_s[r][c4] = kvv;
    }
    __syncthreads();
#pragma unroll
    for (int m = 0; m < 4; ++m) {
      int jl = cc + m * 16;
      int j = jb + jl;
      float s = 0.f;
#pragma unroll
      for (int d4 = 0; d4 < 16; ++d4) {
        float4 qv = qreg[d4];
        float4 kv = *(const float4*)&kv_s[jl][d4 * 4];
        s += qv.x * kv.x + qv.y * kv.y + qv.z * kv.z + qv.w * kv.w;
      }
      s *= 0.125f;                     // 1/sqrt(64)
      s = 50.f * tanhf(s * 0.02f);     // softcap
      bool allow = (j <= i) && (i - j < WIN);
      sc[q][ch * 64 + jl] = allow ? s : -1e30f;
    }
    __syncthreads();
  }
  {
    int wid = tid >> 6, lane = tid & 63;
    int ncols = nch * 64;
    for (int r = wid * 4; r < wid * 4 + 4; ++r) {
      float mx = -1e30f;
      for (int n = lane; n < ncols; n += 64) mx = fmaxf(mx, sc[r][n]);
      for (int off = 32; off; off >>= 1) mx = fmaxf(mx, __shfl_xor(mx, off));
      float sum = 0.f;
      for (int n = lane; n < ncols; n += 64) {
        float p = expf(sc[r][n] - mx);
        sc[r][n] = p; sum += p;
      }
      for (int off = 32; off; off >>= 1) sum += __shfl_xor(sum, off);
      if (lane == 0) row_a[r] = 1.06f / sum;
    }
  }
  __syncthreads();
  float outv[4] = {0.f, 0.f, 0.f, 0.f};
  for (int ch = 0; ch < nch; ++ch) {
    int jb = jstart + ch * 64;
#pragma unroll
    for (int it = 0; it < 4; ++it) {
      int flat4 = tid + it * 256;
      int r = flat4 >> 4, c4 = (flat4 & 15) * 4;
      int j = jb + r;
      float4 vv = make_float4(0.f, 0.f, 0.f, 0.f);
      if (j < S_LEN) vv = *(const float4*)&qkv[(long)j * 2048 + 1536 + kvh * HEADD + c4];
      *(float4*)&kv_s[r][c4] = vv;
    }
    __syncthreads();
    float a = row_a[q];
    for (int jl4 = 0; jl4 < 16; ++jl4) {
      float4 pp = *(const float4*)&sc[q][ch * 64 + jl4 * 4];
#pragma unroll
      for (int u = 0; u < 4; ++u) {
        float p = (&pp.x)[u];
        p = fminf(fmaxf(fmaf(a, p, -0.03f), 0.f), 1.f);   // clip(1.06*p/l - 0.03, 0, 1)
        float4 vv = *(const float4*)&kv_s[jl4 * 4 + u][cc * 4];
        outv[0] += p * vv.x; outv[1] += p * vv.y; outv[2] += p * vv.z; outv[3] += p * vv.w;
      }
    }
    __syncthreads();
  }
  long ob = (long)i * 1024 + hq * HEADD + cc * 4;
  short h0 = f2bf(outv[0]), h1 = f2bf(outv[1]), h2 = f2bf(outv[2]), h3 = f2bf(outv[3]);
  short l0 = f2bf(outv[0] - bf2f(h0)), l1 = f2bf(outv[1] - bf2f(h1));
  short l2 = f2bf(outv[2] - bf2f(h2)), l3 = f2bf(outv[3] - bf2f(h3));
  *(uint2*)&attHi[ob] = make_uint2((unsigned short)h0 | ((unsigned)(unsigned short)h1 << 16),
                                   (unsigned short)h2 | ((unsigned)(unsigned short)h3 << 16));
  *(uint2*)&attLo[ob] = make_uint2((unsigned short)l0 | ((unsigned)(unsigned short)l1 << 16),
                                   (unsigned short)l2 | ((unsigned)(unsigned short)l3 << 16));
}

// ---------------- bf16 MFMA GEMM: C[M,N](f32) (+)= A[M,K] @ Bt[N,K]^T ----------------
template <int ATOMIC>
__global__ __launch_bounds__(256) void k_gemm_bf16(const short* __restrict__ A,
                                                   const short* __restrict__ Bt,
                                                   float* __restrict__ C,
                                                   int K, int ldA, int ldB, int ldC,
                                                   long sA, long sB, long sC) {
  __shared__ short As[128 * 64];
  __shared__ short Bs[128 * 64];
  const int e = blockIdx.z;
  A += (long)e * sA; Bt += (long)e * sB; C += (long)e * sC;
  const int r0 = blockIdx.x * 128, c0 = blockIdx.y * 128;
  const int tid = threadIdx.x;
  const int wid = tid >> 6, lane = tid & 63;
  const int wr = wid >> 1, wc = wid & 1;
  const int lr = lane & 15, lg = lane >> 4;
  f32x4 zero = {0.f, 0.f, 0.f, 0.f};
  f32x4 acc[4][4];
#pragma unroll
  for (int m = 0; m < 4; ++m)
#pragma unroll
    for (int n = 0; n < 4; ++n) acc[m][n] = zero;
  for (int k0 = 0; k0 < K; k0 += 64) {
#pragma unroll
    for (int it = 0; it < 4; ++it) {
      int flat = tid + it * 256;
      int row = flat >> 3, cb = (flat & 7) * 8;
      int d = swz(row, cb);
      *(uint4*)&As[d] = *(const uint4*)&A[(long)(r0 + row) * ldA + k0 + cb];
      *(uint4*)&Bs[d] = *(const uint4*)&Bt[(long)(c0 + row) * ldB + k0 + cb];
    }
    __syncthreads();
#pragma unroll
    for (int kk = 0; kk < 64; kk += 32) {
      bf16x8 af[4], bfr[4];
#pragma unroll
      for (int m = 0; m < 4; ++m) af[m] = *(const bf16x8*)&As[swz(wr * 64 + m * 16 + lr, kk + lg * 8)];
#pragma unroll
      for (int n = 0; n < 4; ++n) bfr[n] = *(const bf16x8*)&Bs[swz(wc * 64 + n * 16 + lr, kk + lg * 8)];
#pragma unroll
      for (int m = 0; m < 4; ++m)
#pragma unroll
        for (int n = 0; n < 4; ++n)
          acc[m][n] = __builtin_amdgcn_mfma_f32_16x16x32_bf16(af[m], bfr[n], acc[m][n], 0, 0, 0);
    }
    __syncthreads();
  }
#pragma unroll
  for (int m = 0; m < 4; ++m)
#pragma unroll
    for (int n = 0; n < 4; ++n) {
      int col = c0 + wc * 64 + n * 16 + lr;
#pragma unroll
      for (int r = 0; r < 4; ++r) {
        int row = r0 + wr * 64 + m * 16 + lg * 4 + r;
        float v = acc[m][n][r];
        if (ATOMIC) atomicAdd(&C[(long)row * ldC + col], v);
        else        C[(long)row * ldC + col] = v;
      }
    }
}

// ---------------- moe activation: a[e,t,f] = bf16( silu(g)*u * w_te ) ----------------
__global__ __launch_bounds__(256) void k_moe_act(const float* __restrict__ gu,
                                                 const float* __restrict__ wd,
                                                 short* __restrict__ aAll,
                                                 int e) {
  long i4 = (long)blockIdx.x * 256 + threadIdx.x;   // 2048*2048/4 = 1M float4
  int t  = (int)(i4 >> 9);
  int f4 = (int)(i4 & 511);
  float wte = wd[t * 4 + e];
  float4 g = ((const float4*)gu)[(long)t * 1024 + f4];
  float4 u = ((const float4*)gu)[(long)t * 1024 + 512 + f4];
  float4 s;
  s.x = wte * u.x * g.x / (1.f + expf(-g.x));
  s.y = wte * u.y * g.y / (1.f + expf(-g.y));
  s.z = wte * u.z * g.z / (1.f + expf(-g.z));
  s.w = wte * u.w * g.w / (1.f + expf(-g.w));
  unsigned lo = (unsigned short)f2bf(s.x) | ((unsigned)(unsigned short)f2bf(s.y) << 16);
  unsigned hi = (unsigned short)f2bf(s.z) | ((unsigned)(unsigned short)f2bf(s.w) << 16);
  ((uint2*)(aAll + ((long)e << 22)))[i4] = make_uint2(lo, hi);
}

extern "C" void kernel_launch(void* const* d_in, const int* in_sizes, int n_in,
                              void* d_out, int out_size, void* d_ws, size_t ws_size,
                              hipStream_t stream) {
  const float* x       = (const float*)d_in[0];
  const float* norm1_w = (const float*)d_in[1];
  const float* wq      = (const float*)d_in[2];
  const float* wk      = (const float*)d_in[3];
  const float* wv      = (const float*)d_in[4];
  const float* wo      = (const float*)d_in[5];
  const float* qn_w    = (const float*)d_in[6];
  const float* kn_w    = (const float*)d_in[7];
  const float* norm2_w = (const float*)d_in[8];
  const float* gate_w  = (const float*)d_in[9];
  const float* w_gate  = (const float*)d_in[10];
  const float* w_up    = (const float*)d_in[11];
  const float* w_down  = (const float*)d_in[12];
  float* out = (float*)d_out;
  char* ws = (char*)d_ws;
  const unsigned long MB = 1ul << 20;

  // workspace map (106 MB total; gu aliases [1,33); guT aliases dead h)
  float* ropeC = (float*)(ws + 0);               // 256 KB
  float* ropeS = (float*)(ws + 256 * 1024);      // 256 KB
  float* qkv   = (float*)(ws + 1 * MB);          // 16 MB  [1,17)
  short* xnHi  = (short*)(ws + 17 * MB);         // 4 MB
  short* xnLo  = (short*)(ws + 21 * MB);         // 4 MB
  short* attHi = (short*)(ws + 25 * MB);         // 4 MB
  short* attLo = (short*)(ws + 29 * MB);         // 4 MB
  float* gu    = (float*)(ws + 1 * MB);          // 32 MB, aliases qkv/xnS/attS (dead by MoE)
  short* qkvWh = (short*)(ws + 33 * MB);         // 4 MB
  short* qkvWl = (short*)(ws + 37 * MB);         // 4 MB
  short* woTh  = (short*)(ws + 41 * MB);         // 2 MB
  short* woTl  = (short*)(ws + 43 * MB);         // 2 MB
  float* h     = (float*)(ws + 45 * MB);         // 8 MB
  short* guT   = (short*)(ws + 45 * MB);         // 8 MB, aliases h (dead after memcpy)
  short* x2b   = (short*)(ws + 53 * MB);         // 4 MB
  float* wd    = (float*)(ws + 57 * MB);         // 32 KB
  short* dT    = (short*)(ws + 58 * MB);         // 16 MB
  short* aAll  = (short*)(ws + 74 * MB);         // 32 MB -> ends 106 MB

  k_rope_tables<<<256, 256, 0, stream>>>(ropeC, ropeS);
  k_rmsnorm<2><<<S_LEN, 256, 0, stream>>>(x, norm1_w, xnHi, xnLo, nullptr, nullptr);
  // transpose+split QKV weights into one Bt (2048 rows x 1024): q|k|v at rows 0|1024|1536
  k_tsplit<<<dim3(32, 32), 256, 0, stream>>>(wq, qkvWh, qkvWl, 1024, 1024);
  k_tsplit<<<dim3(16, 32), 256, 0, stream>>>(wk, qkvWh + 1024 * 1024, qkvWl + 1024 * 1024, 1024, 512);
  k_tsplit<<<dim3(16, 32), 256, 0, stream>>>(wv, qkvWh + 1536 * 1024, qkvWl + 1536 * 1024, 1024, 512);
  k_tsplit<<<dim3(32, 32), 256, 0, stream>>>(wo, woTh, woTl, 1024, 1024);
  // fused QKV projection (split-bf16 ~= fp32): qkv[t][0:1024|1024:1536|1536:2048]
  k_gemm_split<0><<<dim3(16, 16), 256, 0, stream>>>(xnHi, xnLo, qkvWh, qkvWl, nullptr, qkv,
                                                    1024, 1024, 1024, 2048);
  k_rope_rms<<<(S_LEN * 24) / 4, 256, 0, stream>>>(qkv, qn_w, kn_w, ropeC, ropeS);
  k_attn<<<dim3(S_LEN / QB, N_QH), 256, 0, stream>>>(qkv, attHi, attLo);
  // h = x + att @ wo   (split-bf16 ~= fp32)
  k_gemm_split<1><<<dim3(16, 8), 256, 0, stream>>>(attHi, attLo, woTh, woTl, x, h,
                                                   1024, 1024, 1024, 1024);
  k_rmsnorm<3><<<S_LEN, 256, 0, stream>>>(h, norm2_w, x2b, nullptr, gate_w, wd);
  hipMemcpyAsync(out, h, (size_t)S_LEN * H_DIM * sizeof(float), hipMemcpyDeviceToDevice, stream);
  // bf16 down-proj weights (all experts, needed by batched GEMM2)
  for (int e = 0; e < N_EXP; ++e)
    k_transpose_cast<<<dim3(1024 / 32, 2048 / 32), 256, 0, stream>>>(
        w_down + (long)e * FF_DIM * H_DIM, dT + (long)e * H_DIM * FF_DIM, 2048, 1024);
  // per-expert: transpose gate/up -> guT (aliases dead h), GEMM1 (N=4096), act -> aAll[e]
  for (int e = 0; e < N_EXP; ++e) {
    k_transpose_cast<<<dim3(2048 / 32, 1024 / 32), 256, 0, stream>>>(
        w_gate + (long)e * H_DIM * FF_DIM, guT, 1024, 2048);
    k_transpose_cast<<<dim3(2048 / 32, 1024 / 32), 256, 0, stream>>>(
        w_up + (long)e * H_DIM * FF_DIM, guT + (long)FF_DIM * H_DIM, 1024, 2048);
    k_gemm_bf16<0><<<dim3(16, 32), 256, 0, stream>>>(x2b, guT, gu, 1024, 1024, 1024, 4096, 0, 0, 0);
    k_moe_act<<<4096, 256, 0, stream>>>(gu, wd, aAll, e);
  }
  // batched GEMM2 over experts: out += a[e] @ w_down[e]  (atomicAdd epilogue)
  k_gemm_bf16<1><<<dim3(16, 8, N_EXP), 256, 0, stream>>>(
      aAll, dT, out, 2048, 2048, 2048, 1024,
      (long)S_LEN * FF_DIM, (long)H_DIM * FF_DIM, 0);
}